// Round 3
// baseline (52.043 us; speedup 1.0000x reference)
//
#include <hip/hip_runtime.h>

// out[i*1536 + j] = -(1/0.924458) * sum_{a,b} w[a][b] * x[3i+a][3j+b]
// x: 4608x4608 f32, w: 3x3 f32, out: 1536x1536 f32.
//
// Single-round residency version: GRID = 256 blocks (exactly 1 per CU),
// BLOCK = 768 (12 waves/CU, fully resident, zero tail round). Each thread
// computes 12 consecutive outputs: 3 rows x 9 independent float4 loads
// (9-deep MLP), all register-indexed via full unroll.

constexpr int W     = 4608;   // input row stride (floats)
constexpr int NH    = 1536;   // output cols / rows
constexpr int OPT   = 12;     // outputs per thread
constexpr int TPR   = NH / OPT;        // 128 threads per output row
constexpr int BLOCK = 768;             // 12 waves
constexpr int GRID  = (NH * TPR) / BLOCK; // 196608 / 768 = 256

__global__ __launch_bounds__(BLOCK) void conv3x3_s3_wide(
    const float* __restrict__ x,
    const float* __restrict__ w,
    float* __restrict__ out)
{
    const int g = blockIdx.x * BLOCK + threadIdx.x;
    const int i = g >> 7;          // output row   [0,1536)
    const int q = g & 127;         // segment      [0,128)

    // 12 outputs -> input cols 36q .. 36q+35 of rows 3i..3i+2.
    // 36q floats = 144q bytes: 16B-aligned.
    const float* base = x + (size_t)(3 * i) * W + 36 * q;

    const float w00 = w[0], w01 = w[1], w02 = w[2];
    const float w10 = w[3], w11 = w[4], w12 = w[5];
    const float w20 = w[6], w21 = w[7], w22 = w[8];

    float acc[OPT];
    #pragma unroll
    for (int k = 0; k < OPT; ++k) acc[k] = 0.f;

    #pragma unroll
    for (int a = 0; a < 3; ++a) {
        const float4* p = reinterpret_cast<const float4*>(base + (size_t)a * W);

        // 9 independent float4 loads, then fully static unpack.
        float f[36];
        #pragma unroll
        for (int u = 0; u < 9; ++u) {
            const float4 v = p[u];
            f[4 * u + 0] = v.x;
            f[4 * u + 1] = v.y;
            f[4 * u + 2] = v.z;
            f[4 * u + 3] = v.w;
        }

        float wa0, wa1, wa2;
        if (a == 0)      { wa0 = w00; wa1 = w01; wa2 = w02; }
        else if (a == 1) { wa0 = w10; wa1 = w11; wa2 = w12; }
        else             { wa0 = w20; wa1 = w21; wa2 = w22; }

        #pragma unroll
        for (int k = 0; k < OPT; ++k)
            acc[k] += wa0 * f[3 * k] + wa1 * f[3 * k + 1] + wa2 * f[3 * k + 2];
    }

    const float scale = -1.0f / 0.924458f;

    // 12 outputs = 3 float4 stores; out offset 12q floats = 48q B, 16B-aligned.
    float* o = out + (size_t)i * NH + 12 * q;
    #pragma unroll
    for (int s = 0; s < 3; ++s) {
        float4 r4;
        r4.x = acc[4 * s + 0] * scale;
        r4.y = acc[4 * s + 1] * scale;
        r4.z = acc[4 * s + 2] * scale;
        r4.w = acc[4 * s + 3] * scale;
        reinterpret_cast<float4*>(o)[s] = r4;
    }
}

extern "C" void kernel_launch(void* const* d_in, const int* in_sizes, int n_in,
                              void* d_out, int out_size, void* d_ws, size_t ws_size,
                              hipStream_t stream)
{
    const float* x = (const float*)d_in[0];   // 4608*4608
    const float* w = (const float*)d_in[1];   // 9
    float* out = (float*)d_out;               // 1536*1536

    conv3x3_s3_wide<<<GRID, BLOCK, 0, stream>>>(x, w, out);
}

// Round 4
// 19.829 us; speedup vs baseline: 2.6245x; 2.6245x over previous
//
#include <hip/hip_runtime.h>

// out[i*1536 + j] = -(1/0.924458) * sum_{a,b} w[a][b] * x[3i+a][3j+b]
// x: 4608x4608 f32, w: 3x3 f32, out: 1536x1536 f32.
//
// Persistent tail-free version with v0's proven access pattern.
// Grid = 256 blocks x 768 threads = 12 waves/CU, exactly 1 block/CU,
// fully resident, zero second round. Each thread runs 3 quad-tasks at
// grid stride; each task = v0's body: 3 rows x 3 float4 loads
// (48 B lane stride), 4 outputs, one contiguous float4 store.

constexpr int W      = 4608;           // input row stride (floats)
constexpr int NH     = 1536;           // output rows/cols
constexpr int QPR    = NH / 4;         // 384 output quads per row
constexpr int NQUADS = NH * QPR;       // 589824 total quad-tasks
constexpr int BLOCK  = 768;            // 12 waves
constexpr int GRID   = 256;            // 1 block per CU
constexpr int STRIDE = BLOCK * GRID;   // 196608 threads
constexpr int TASKS  = NQUADS / STRIDE; // 3

__global__ __launch_bounds__(BLOCK) void conv3x3_s3_persist(
    const float* __restrict__ x,
    const float* __restrict__ w,
    float* __restrict__ out)
{
    const int t0 = blockIdx.x * BLOCK + threadIdx.x;

    const float w00 = w[0], w01 = w[1], w02 = w[2];
    const float w10 = w[3], w11 = w[4], w12 = w[5];
    const float w20 = w[6], w21 = w[7], w22 = w[8];

    const float scale = -1.0f / 0.924458f;

    #pragma unroll
    for (int k = 0; k < TASKS; ++k) {
        const unsigned tau = (unsigned)(t0 + k * STRIDE);
        const unsigned row = tau / QPR;          // magic-mul const divide
        const unsigned q   = tau - row * QPR;    // quad within row [0,384)

        // input: rows 3*row .. 3*row+2, cols 12q .. 12q+11 (48q B, 16B-aligned)
        const float* base = x + (size_t)(3 * row) * W + 12 * q;

        float4 v[9];
        #pragma unroll
        for (int a = 0; a < 3; ++a) {
            const float4* p = reinterpret_cast<const float4*>(base + (size_t)a * W);
            v[3 * a + 0] = p[0];
            v[3 * a + 1] = p[1];
            v[3 * a + 2] = p[2];
        }

        float acc0 = 0.f, acc1 = 0.f, acc2 = 0.f, acc3 = 0.f;
        #pragma unroll
        for (int a = 0; a < 3; ++a) {
            float wa0, wa1, wa2;
            if (a == 0)      { wa0 = w00; wa1 = w01; wa2 = w02; }
            else if (a == 1) { wa0 = w10; wa1 = w11; wa2 = w12; }
            else             { wa0 = w20; wa1 = w21; wa2 = w22; }

            const float4 v0 = v[3 * a + 0];
            const float4 v1 = v[3 * a + 1];
            const float4 v2 = v[3 * a + 2];

            acc0 += wa0 * v0.x + wa1 * v0.y + wa2 * v0.z;
            acc1 += wa0 * v0.w + wa1 * v1.x + wa2 * v1.y;
            acc2 += wa0 * v1.z + wa1 * v1.w + wa2 * v2.x;
            acc3 += wa0 * v2.y + wa1 * v2.z + wa2 * v2.w;
        }

        float4 r4;
        r4.x = acc0 * scale;
        r4.y = acc1 * scale;
        r4.z = acc2 * scale;
        r4.w = acc3 * scale;

        // output: row `row`, cols 4q..4q+3 (16q B, 16B-aligned), lane-contiguous
        float* o = out + (size_t)row * NH + 4 * q;
        *reinterpret_cast<float4*>(o) = r4;
    }
}

extern "C" void kernel_launch(void* const* d_in, const int* in_sizes, int n_in,
                              void* d_out, int out_size, void* d_ws, size_t ws_size,
                              hipStream_t stream)
{
    const float* x = (const float*)d_in[0];   // 4608*4608
    const float* w = (const float*)d_in[1];   // 9
    float* out = (float*)d_out;               // 1536*1536

    conv3x3_s3_persist<<<GRID, BLOCK, 0, stream>>>(x, w, out);
}